// Round 1
// baseline (2834.303 us; speedup 1.0000x reference)
//
#include <hip/hip_runtime.h>

// ---------------------------------------------------------------------------
// MHA block: q,k,v = x@W*.T + b*; causal softmax attention; out = preout@Wo.T+bo
// B=2, S=2048, D=1024, NH=16, HD=64. fp32 I/O, bf16 internal (MFMA for GEMMs).
// ---------------------------------------------------------------------------

#define DEV __device__ __forceinline__

typedef __bf16 bf16x8 __attribute__((ext_vector_type(8)));
typedef float  f32x4  __attribute__((ext_vector_type(4)));
typedef unsigned short u16;
typedef u16 u16x8 __attribute__((ext_vector_type(8)));
typedef u16 u16x4 __attribute__((ext_vector_type(4)));

constexpr int BB  = 2;
constexpr int S   = 2048;
constexpr int DM  = 1024;
constexpr int HD  = 64;
constexpr int NH  = 16;
constexpr int MT  = BB * S;      // 4096 token rows

DEV u16 f2bf(float f) {
    unsigned u = __float_as_uint(f);
    unsigned r = u + 0x7fffu + ((u >> 16) & 1u);   // RNE
    return (u16)(r >> 16);
}
DEV float bf2f(u16 b) { return __uint_as_float(((unsigned)b) << 16); }

// ---------------------------------------------------------------------------
// fp32 -> bf16 convert (vectorized x4)
// ---------------------------------------------------------------------------
__global__ void cvt_f32_bf16(const float* __restrict__ in, u16* __restrict__ out, int n4) {
    int i = blockIdx.x * blockDim.x + threadIdx.x;
    if (i < n4) {
        float4 v = reinterpret_cast<const float4*>(in)[i];
        u16x4 o;
        o[0] = f2bf(v.x); o[1] = f2bf(v.y); o[2] = f2bf(v.z); o[3] = f2bf(v.w);
        reinterpret_cast<u16x4*>(out)[i] = o;
    }
}

// ---------------------------------------------------------------------------
// GEMM: C[M x N] = A[M x K](bf16) @ W[N x K]^T(bf16) + bias[N](f32)
// 4 waves/block; each wave a 32x32 tile (2x2 frags of 16x16x32 MFMA).
// Block tile: 128 rows x 32 cols. Grid: (M/128, N/32).
// ---------------------------------------------------------------------------
template <bool OUT_BF16>
__global__ __launch_bounds__(256) void gemm_bt(const u16* __restrict__ A,
                                               const u16* __restrict__ W,
                                               const float* __restrict__ bias,
                                               void* __restrict__ Cout,
                                               int M, int N, int K) {
    const int lane = threadIdx.x & 63;
    const int wv   = threadIdx.x >> 6;
    const int m0   = blockIdx.x * 128 + wv * 32;
    const int n0   = blockIdx.y * 32;
    const int rA   = lane & 15;          // fragment row/col within 16
    const int kg   = (lane >> 4) * 8;    // k-group base

    f32x4 acc[2][2] = {{{0,0,0,0},{0,0,0,0}},{{0,0,0,0},{0,0,0,0}}};

    const u16* Ar0 = A + (size_t)(m0 + rA) * K + kg;
    const u16* Ar1 = Ar0 + (size_t)16 * K;
    const u16* Wr0 = W + (size_t)(n0 + rA) * K + kg;
    const u16* Wr1 = Wr0 + (size_t)16 * K;

    for (int kb = 0; kb < K; kb += 32) {
        bf16x8 a0 = *reinterpret_cast<const bf16x8*>(Ar0 + kb);
        bf16x8 a1 = *reinterpret_cast<const bf16x8*>(Ar1 + kb);
        bf16x8 b0 = *reinterpret_cast<const bf16x8*>(Wr0 + kb);
        bf16x8 b1 = *reinterpret_cast<const bf16x8*>(Wr1 + kb);
        acc[0][0] = __builtin_amdgcn_mfma_f32_16x16x32_bf16(a0, b0, acc[0][0], 0, 0, 0);
        acc[0][1] = __builtin_amdgcn_mfma_f32_16x16x32_bf16(a0, b1, acc[0][1], 0, 0, 0);
        acc[1][0] = __builtin_amdgcn_mfma_f32_16x16x32_bf16(a1, b0, acc[1][0], 0, 0, 0);
        acc[1][1] = __builtin_amdgcn_mfma_f32_16x16x32_bf16(a1, b1, acc[1][1], 0, 0, 0);
    }

    const int rr = (lane >> 4) * 4;
    const int cc = lane & 15;
    #pragma unroll
    for (int i = 0; i < 2; ++i) {
        #pragma unroll
        for (int j = 0; j < 2; ++j) {
            const int col = n0 + j * 16 + cc;
            const float bv = bias[col];
            #pragma unroll
            for (int r = 0; r < 4; ++r) {
                const int row = m0 + i * 16 + rr + r;
                const float v = acc[i][j][r] + bv;
                if (OUT_BF16)
                    ((u16*)Cout)[(size_t)row * N + col] = f2bf(v);
                else
                    ((float*)Cout)[(size_t)row * N + col] = v;
            }
        }
    }
}

// ---------------------------------------------------------------------------
// Causal flash attention, fp32 VALU. One query row per thread.
// Block: 128 threads handles 128 consecutive queries of one (b, h).
// K/V staged per 64-key tile into LDS as fp32.
// Q pre-scaled by 1/sqrt(HD) = 0.125.
// ---------------------------------------------------------------------------
__global__ __launch_bounds__(128) void attn_flash(const u16* __restrict__ Qg,
                                                  const u16* __restrict__ Kg,
                                                  const u16* __restrict__ Vg,
                                                  u16* __restrict__ Pg) {
    const int bh  = blockIdx.x;            // b*NH + h
    const int b   = bh >> 4;
    const int h   = bh & 15;
    const int tid = threadIdx.x;
    const int q   = blockIdx.y * 128 + tid;

    __shared__ float kl[64][HD];
    __shared__ float vl[64][HD];

    const size_t rowQ = (size_t)(b * S + q) * DM + h * HD;

    float qr[HD];
    #pragma unroll
    for (int t = 0; t < 8; ++t) {
        u16x8 v = *reinterpret_cast<const u16x8*>(&Qg[rowQ + t * 8]);
        #pragma unroll
        for (int i = 0; i < 8; ++i) qr[t * 8 + i] = bf2f(v[i]) * 0.125f;
    }

    float o[HD];
    #pragma unroll
    for (int d = 0; d < HD; ++d) o[d] = 0.0f;
    float m = -1e30f, l = 0.0f;

    const int ntiles = (blockIdx.y + 1) * 2;   // keys up to block's max q, tiles of 64

    for (int t = 0; t < ntiles; ++t) {
        const int j0 = t * 64;
        __syncthreads();   // protect previous tile from overwrite
        // stage K/V tile: 64 rows x 64 cols, 8-elem chunks; 512 chunks / 128 thr
        for (int idx = tid; idx < 512; idx += 128) {
            const int r  = idx >> 3;
            const int c8 = (idx & 7) << 3;
            const size_t g = (size_t)(b * S + j0 + r) * DM + h * HD + c8;
            u16x8 kv = *reinterpret_cast<const u16x8*>(&Kg[g]);
            u16x8 vv = *reinterpret_cast<const u16x8*>(&Vg[g]);
            #pragma unroll
            for (int i = 0; i < 8; ++i) {
                kl[r][c8 + i] = bf2f(kv[i]);
                vl[r][c8 + i] = bf2f(vv[i]);
            }
        }
        __syncthreads();

        int jlim = q - j0 + 1;
        if (jlim > 64) jlim = 64;
        for (int j = 0; j < jlim; ++j) {
            const float4* kj = reinterpret_cast<const float4*>(&kl[j][0]);
            const float4* vj = reinterpret_cast<const float4*>(&vl[j][0]);
            float s0 = 0.f, s1 = 0.f, s2 = 0.f, s3 = 0.f;
            #pragma unroll
            for (int u = 0; u < 16; ++u) {
                float4 kk = kj[u];
                s0 = fmaf(qr[4 * u + 0], kk.x, s0);
                s1 = fmaf(qr[4 * u + 1], kk.y, s1);
                s2 = fmaf(qr[4 * u + 2], kk.z, s2);
                s3 = fmaf(qr[4 * u + 3], kk.w, s3);
            }
            const float s  = (s0 + s1) + (s2 + s3);
            const float mn = fmaxf(m, s);
            const float c  = __expf(m - mn);
            const float p  = __expf(s - mn);
            l = fmaf(l, c, p);
            #pragma unroll
            for (int u = 0; u < 16; ++u) {
                float4 vv = vj[u];
                o[4 * u + 0] = fmaf(o[4 * u + 0], c, p * vv.x);
                o[4 * u + 1] = fmaf(o[4 * u + 1], c, p * vv.y);
                o[4 * u + 2] = fmaf(o[4 * u + 2], c, p * vv.z);
                o[4 * u + 3] = fmaf(o[4 * u + 3], c, p * vv.w);
            }
            m = mn;
        }
    }

    const float inv = 1.0f / l;
    #pragma unroll
    for (int t = 0; t < 8; ++t) {
        u16x8 ov;
        #pragma unroll
        for (int i = 0; i < 8; ++i) ov[i] = f2bf(o[t * 8 + i] * inv);
        *reinterpret_cast<u16x8*>(&Pg[rowQ + t * 8]) = ov;
    }
}

// ---------------------------------------------------------------------------
// launch
// ---------------------------------------------------------------------------
extern "C" void kernel_launch(void* const* d_in, const int* in_sizes, int n_in,
                              void* d_out, int out_size, void* d_ws, size_t ws_size,
                              hipStream_t stream) {
    const float* x  = (const float*)d_in[0];
    const float* Wq = (const float*)d_in[1];
    const float* bq = (const float*)d_in[2];
    const float* Wk = (const float*)d_in[3];
    const float* bk = (const float*)d_in[4];
    const float* Wv = (const float*)d_in[5];
    const float* bv = (const float*)d_in[6];
    const float* Wo = (const float*)d_in[7];
    const float* bo = (const float*)d_in[8];
    float* out = (float*)d_out;

    // workspace layout (all bf16 = u16)
    u16* xb  = (u16*)d_ws;                     // MT*DM   = 4194304
    u16* wqb = xb  + (size_t)MT * DM;          // DM*DM   = 1048576
    u16* wkb = wqb + (size_t)DM * DM;
    u16* wvb = wkb + (size_t)DM * DM;
    u16* wob = wvb + (size_t)DM * DM;
    u16* Qb  = wob + (size_t)DM * DM;          // MT*DM
    u16* Kb  = Qb  + (size_t)MT * DM;
    u16* Vb  = Kb  + (size_t)MT * DM;
    u16* Pb  = Vb  + (size_t)MT * DM;          // preout bf16

    const int nX = MT * DM;       // 4194304
    const int nW = DM * DM;       // 1048576

    // converts
    cvt_f32_bf16<<<dim3((nX / 4 + 255) / 256), dim3(256), 0, stream>>>(x,  xb,  nX / 4);
    cvt_f32_bf16<<<dim3((nW / 4 + 255) / 256), dim3(256), 0, stream>>>(Wq, wqb, nW / 4);
    cvt_f32_bf16<<<dim3((nW / 4 + 255) / 256), dim3(256), 0, stream>>>(Wk, wkb, nW / 4);
    cvt_f32_bf16<<<dim3((nW / 4 + 255) / 256), dim3(256), 0, stream>>>(Wv, wvb, nW / 4);
    cvt_f32_bf16<<<dim3((nW / 4 + 255) / 256), dim3(256), 0, stream>>>(Wo, wob, nW / 4);

    // projections: Q/K/V = xb @ W^T + b  (output bf16)
    dim3 ggrid(MT / 128, DM / 32);
    gemm_bt<true><<<ggrid, dim3(256), 0, stream>>>(xb, wqb, bq, Qb, MT, DM, DM);
    gemm_bt<true><<<ggrid, dim3(256), 0, stream>>>(xb, wkb, bk, Kb, MT, DM, DM);
    gemm_bt<true><<<ggrid, dim3(256), 0, stream>>>(xb, wvb, bv, Vb, MT, DM, DM);

    // causal flash attention -> Pb (bf16)
    attn_flash<<<dim3(BB * NH, S / 128), dim3(128), 0, stream>>>(Qb, Kb, Vb, Pb);

    // output projection: out = Pb @ Wo^T + bo (fp32)
    gemm_bt<false><<<ggrid, dim3(256), 0, stream>>>(Pb, wob, bo, out, MT, DM, DM);
}

// Round 2
// 389.606 us; speedup vs baseline: 7.2748x; 7.2748x over previous
//
#include <hip/hip_runtime.h>

// ---------------------------------------------------------------------------
// MHA block: q,k,v = x@W*.T + b*; causal softmax attention; out = preout@Wo.T+bo
// B=2, S=2048, D=1024, NH=16, HD=64. fp32 I/O, bf16 internal (MFMA everywhere).
// ---------------------------------------------------------------------------

#define DEV __device__ __forceinline__

typedef __bf16 bf16x8 __attribute__((ext_vector_type(8)));
typedef float  f32x4  __attribute__((ext_vector_type(4)));
typedef unsigned short u16;
typedef u16 u16x8 __attribute__((ext_vector_type(8)));
typedef u16 u16x4 __attribute__((ext_vector_type(4)));
typedef u16 u16x2 __attribute__((ext_vector_type(2)));

constexpr int BB  = 2;
constexpr int S   = 2048;
constexpr int DM  = 1024;
constexpr int HD  = 64;
constexpr int NH  = 16;
constexpr int MT  = BB * S;      // 4096 token rows

DEV u16 f2bf(float f) {
    unsigned u = __float_as_uint(f);
    unsigned r = u + 0x7fffu + ((u >> 16) & 1u);   // RNE
    return (u16)(r >> 16);
}
DEV float bf2f(u16 b) { return __uint_as_float(((unsigned)b) << 16); }

// ---------------------------------------------------------------------------
// fp32 -> bf16 convert (vectorized x4)
// ---------------------------------------------------------------------------
__global__ void cvt_f32_bf16(const float* __restrict__ in, u16* __restrict__ out, int n4) {
    int i = blockIdx.x * blockDim.x + threadIdx.x;
    if (i < n4) {
        float4 v = reinterpret_cast<const float4*>(in)[i];
        u16x4 o;
        o[0] = f2bf(v.x); o[1] = f2bf(v.y); o[2] = f2bf(v.z); o[3] = f2bf(v.w);
        reinterpret_cast<u16x4*>(out)[i] = o;
    }
}

// ---------------------------------------------------------------------------
// GEMM: C[M x N] = A[M x K](bf16) @ W[N x K]^T(bf16) + bias[N](f32)
// 4 waves/block; each wave a 32x32 tile (2x2 frags of 16x16x32 MFMA).
// Block tile: 128 rows x 32 cols. Grid: (M/128, N/32).
// ---------------------------------------------------------------------------
template <bool OUT_BF16>
__global__ __launch_bounds__(256) void gemm_bt(const u16* __restrict__ A,
                                               const u16* __restrict__ W,
                                               const float* __restrict__ bias,
                                               void* __restrict__ Cout,
                                               int M, int N, int K) {
    const int lane = threadIdx.x & 63;
    const int wv   = threadIdx.x >> 6;
    const int m0   = blockIdx.x * 128 + wv * 32;
    const int n0   = blockIdx.y * 32;
    const int rA   = lane & 15;          // fragment row/col within 16
    const int kg   = (lane >> 4) * 8;    // k-group base

    f32x4 acc[2][2] = {{{0,0,0,0},{0,0,0,0}},{{0,0,0,0},{0,0,0,0}}};

    const u16* Ar0 = A + (size_t)(m0 + rA) * K + kg;
    const u16* Ar1 = Ar0 + (size_t)16 * K;
    const u16* Wr0 = W + (size_t)(n0 + rA) * K + kg;
    const u16* Wr1 = Wr0 + (size_t)16 * K;

    for (int kb = 0; kb < K; kb += 32) {
        bf16x8 a0 = *reinterpret_cast<const bf16x8*>(Ar0 + kb);
        bf16x8 a1 = *reinterpret_cast<const bf16x8*>(Ar1 + kb);
        bf16x8 b0 = *reinterpret_cast<const bf16x8*>(Wr0 + kb);
        bf16x8 b1 = *reinterpret_cast<const bf16x8*>(Wr1 + kb);
        acc[0][0] = __builtin_amdgcn_mfma_f32_16x16x32_bf16(a0, b0, acc[0][0], 0, 0, 0);
        acc[0][1] = __builtin_amdgcn_mfma_f32_16x16x32_bf16(a0, b1, acc[0][1], 0, 0, 0);
        acc[1][0] = __builtin_amdgcn_mfma_f32_16x16x32_bf16(a1, b0, acc[1][0], 0, 0, 0);
        acc[1][1] = __builtin_amdgcn_mfma_f32_16x16x32_bf16(a1, b1, acc[1][1], 0, 0, 0);
    }

    const int rr = (lane >> 4) * 4;
    const int cc = lane & 15;
    #pragma unroll
    for (int i = 0; i < 2; ++i) {
        #pragma unroll
        for (int j = 0; j < 2; ++j) {
            const int col = n0 + j * 16 + cc;
            const float bv = bias[col];
            #pragma unroll
            for (int r = 0; r < 4; ++r) {
                const int row = m0 + i * 16 + rr + r;
                const float v = acc[i][j][r] + bv;
                if (OUT_BF16)
                    ((u16*)Cout)[(size_t)row * N + col] = f2bf(v);
                else
                    ((float*)Cout)[(size_t)row * N + col] = v;
            }
        }
    }
}

// ---------------------------------------------------------------------------
// Causal flash attention with MFMA.
// Block: 256 threads = 4 waves, handles 128 queries of one (b,h).
// Wave w owns queries [q0 + 32w, q0 + 32w + 31] as 2 sub-tiles of 16.
// KV tiles of 64 keys staged in LDS (K natural rows; V transposed Vt[d][k]).
// Per tile: S = mfma(Qfrag, Kfrag) -> softmax in C-layout (shfl_xor reduce)
//           -> P bf16 via per-wave LDS buffer -> O += mfma(Pfrag, Vtfrag).
// ---------------------------------------------------------------------------
__global__ __launch_bounds__(256) void attn_mfma(const u16* __restrict__ Qg,
                                                 const u16* __restrict__ Kg,
                                                 const u16* __restrict__ Vg,
                                                 u16* __restrict__ Pg) {
    const int bh = blockIdx.x;
    const int b  = bh >> 4, h = bh & 15;
    const int yy = blockIdx.y;
    // pair short and long causal blocks for load balance
    const int qblk = (yy & 1) ? (15 - (yy >> 1)) : (yy >> 1);
    const int q0   = qblk * 128;
    const int tid  = threadIdx.x;
    const int w    = tid >> 6;
    const int lane = tid & 63;
    const int ln   = lane & 15;
    const int g    = lane >> 4;
    const int kg8  = g * 8;

    __shared__ __align__(16) u16 Kl[64][72];
    __shared__ __align__(16) u16 Vt[64][72];      // Vt[d][key]
    __shared__ __align__(16) u16 Pl[4][32][72];   // per-wave P buffer

    // Q fragments for this wave's 32 queries (2 sub-tiles x 2 k-chunks)
    bf16x8 qf[2][2];
    const int qw = q0 + w * 32;
    #pragma unroll
    for (int i = 0; i < 2; ++i)
        #pragma unroll
        for (int kk = 0; kk < 2; ++kk)
            qf[i][kk] = *reinterpret_cast<const bf16x8*>(
                &Qg[(size_t)(b * S + qw + i * 16 + ln) * DM + h * HD + kk * 32 + kg8]);

    f32x4 o[2][4] = {};           // [qsub][dtile], rows=(g*4+r) queries, col=d
    float m[2][4], l[2][4];
    #pragma unroll
    for (int i = 0; i < 2; ++i)
        #pragma unroll
        for (int r = 0; r < 4; ++r) { m[i][r] = -1e30f; l[i][r] = 0.0f; }

    const int ntiles = qblk * 2 + 2;
    for (int t = 0; t < ntiles; ++t) {
        const int j0 = t * 64;
        __syncthreads();
        // ---- stage K tile (rows natural) ----
        #pragma unroll
        for (int it = 0; it < 2; ++it) {
            const int idx = it * 256 + tid;            // 0..511
            const int r   = idx >> 3;
            const int c8  = (idx & 7) << 3;
            u16x8 kv = *reinterpret_cast<const u16x8*>(
                &Kg[(size_t)(b * S + j0 + r) * DM + h * HD + c8]);
            *reinterpret_cast<u16x8*>(&Kl[r][c8]) = kv;
        }
        // ---- stage V transposed: thread handles rows 2p,2p+1, dims c8..c8+7 ----
        {
            const int c8 = (tid & 7) << 3;
            const int p  = tid >> 3;                   // 0..31
            const size_t gb = (size_t)(b * S + j0 + 2 * p) * DM + h * HD + c8;
            u16x8 v0 = *reinterpret_cast<const u16x8*>(&Vg[gb]);
            u16x8 v1 = *reinterpret_cast<const u16x8*>(&Vg[gb + DM]);
            #pragma unroll
            for (int i2 = 0; i2 < 8; ++i2) {
                u16x2 pr; pr[0] = v0[i2]; pr[1] = v1[i2];
                *reinterpret_cast<u16x2*>(&Vt[c8 + i2][2 * p]) = pr;
            }
        }
        __syncthreads();

        // ---- QK^T: S[2][4] tiles, reuse K frags across qsubs ----
        f32x4 s[2][4] = {};
        #pragma unroll
        for (int kk = 0; kk < 2; ++kk)
            #pragma unroll
            for (int c = 0; c < 4; ++c) {
                bf16x8 kf = *reinterpret_cast<const bf16x8*>(&Kl[c * 16 + ln][kk * 32 + kg8]);
                s[0][c] = __builtin_amdgcn_mfma_f32_16x16x32_bf16(qf[0][kk], kf, s[0][c], 0, 0, 0);
                s[1][c] = __builtin_amdgcn_mfma_f32_16x16x32_bf16(qf[1][kk], kf, s[1][c], 0, 0, 0);
            }

        // ---- online softmax per qsub ----
        #pragma unroll
        for (int i = 0; i < 2; ++i) {
            const int qb = qw + i * 16 + g * 4;   // query row base for reg r
            float tm[4];
            #pragma unroll
            for (int r = 0; r < 4; ++r) {
                #pragma unroll
                for (int c = 0; c < 4; ++c) {
                    float v = s[i][c][r] * 0.125f;
                    if (j0 + c * 16 + ln > qb + r) v = -1e30f;
                    s[i][c][r] = v;
                }
                tm[r] = fmaxf(fmaxf(s[i][0][r], s[i][1][r]), fmaxf(s[i][2][r], s[i][3][r]));
            }
            #pragma unroll
            for (int mk = 1; mk <= 8; mk <<= 1)
                #pragma unroll
                for (int r = 0; r < 4; ++r)
                    tm[r] = fmaxf(tm[r], __shfl_xor(tm[r], mk, 64));
            float cr[4], ts[4];
            #pragma unroll
            for (int r = 0; r < 4; ++r) {
                const float mn = fmaxf(m[i][r], tm[r]);
                cr[r] = __expf(m[i][r] - mn);
                m[i][r] = mn;
                ts[r] = 0.0f;
                #pragma unroll
                for (int c = 0; c < 4; ++c) {
                    const float p = __expf(s[i][c][r] - mn);
                    s[i][c][r] = p;
                    ts[r] += p;
                }
            }
            #pragma unroll
            for (int mk = 1; mk <= 8; mk <<= 1)
                #pragma unroll
                for (int r = 0; r < 4; ++r)
                    ts[r] += __shfl_xor(ts[r], mk, 64);
            #pragma unroll
            for (int r = 0; r < 4; ++r)
                l[i][r] = l[i][r] * cr[r] + ts[r];
            // write P to per-wave LDS (bf16), row=query, col=key
            #pragma unroll
            for (int c = 0; c < 4; ++c)
                #pragma unroll
                for (int r = 0; r < 4; ++r)
                    Pl[w][i * 16 + g * 4 + r][c * 16 + ln] = f2bf(s[i][c][r]);
            // rescale O accumulator
            #pragma unroll
            for (int d = 0; d < 4; ++d)
                #pragma unroll
                for (int r = 0; r < 4; ++r)
                    o[i][d][r] *= cr[r];
        }

        // ---- PV: O += P @ Vt^T ----
        #pragma unroll
        for (int kk = 0; kk < 2; ++kk) {
            bf16x8 pf0 = *reinterpret_cast<const bf16x8*>(&Pl[w][ln][kk * 32 + kg8]);
            bf16x8 pf1 = *reinterpret_cast<const bf16x8*>(&Pl[w][16 + ln][kk * 32 + kg8]);
            #pragma unroll
            for (int d = 0; d < 4; ++d) {
                bf16x8 vf = *reinterpret_cast<const bf16x8*>(&Vt[d * 16 + ln][kk * 32 + kg8]);
                o[0][d] = __builtin_amdgcn_mfma_f32_16x16x32_bf16(pf0, vf, o[0][d], 0, 0, 0);
                o[1][d] = __builtin_amdgcn_mfma_f32_16x16x32_bf16(pf1, vf, o[1][d], 0, 0, 0);
            }
        }
    }

    // ---- epilogue: normalize and store preout (bf16) ----
    #pragma unroll
    for (int i = 0; i < 2; ++i) {
        float inv[4];
        #pragma unroll
        for (int r = 0; r < 4; ++r) inv[r] = 1.0f / l[i][r];
        #pragma unroll
        for (int d = 0; d < 4; ++d)
            #pragma unroll
            for (int r = 0; r < 4; ++r) {
                const int qg_ = qw + i * 16 + g * 4 + r;
                Pg[(size_t)(b * S + qg_) * DM + h * HD + d * 16 + ln] = f2bf(o[i][d][r] * inv[r]);
            }
    }
}

// ---------------------------------------------------------------------------
// launch
// ---------------------------------------------------------------------------
extern "C" void kernel_launch(void* const* d_in, const int* in_sizes, int n_in,
                              void* d_out, int out_size, void* d_ws, size_t ws_size,
                              hipStream_t stream) {
    const float* x  = (const float*)d_in[0];
    const float* Wq = (const float*)d_in[1];
    const float* bq = (const float*)d_in[2];
    const float* Wk = (const float*)d_in[3];
    const float* bk = (const float*)d_in[4];
    const float* Wv = (const float*)d_in[5];
    const float* bv = (const float*)d_in[6];
    const float* Wo = (const float*)d_in[7];
    const float* bo = (const float*)d_in[8];
    float* out = (float*)d_out;

    // workspace layout (all bf16 = u16)
    u16* xb  = (u16*)d_ws;                     // MT*DM
    u16* wqb = xb  + (size_t)MT * DM;          // DM*DM
    u16* wkb = wqb + (size_t)DM * DM;
    u16* wvb = wkb + (size_t)DM * DM;
    u16* wob = wvb + (size_t)DM * DM;
    u16* Qb  = wob + (size_t)DM * DM;          // MT*DM
    u16* Kb  = Qb  + (size_t)MT * DM;
    u16* Vb  = Kb  + (size_t)MT * DM;
    u16* Pb  = Vb  + (size_t)MT * DM;          // preout bf16

    const int nX = MT * DM;
    const int nW = DM * DM;

    // converts
    cvt_f32_bf16<<<dim3((nX / 4 + 255) / 256), dim3(256), 0, stream>>>(x,  xb,  nX / 4);
    cvt_f32_bf16<<<dim3((nW / 4 + 255) / 256), dim3(256), 0, stream>>>(Wq, wqb, nW / 4);
    cvt_f32_bf16<<<dim3((nW / 4 + 255) / 256), dim3(256), 0, stream>>>(Wk, wkb, nW / 4);
    cvt_f32_bf16<<<dim3((nW / 4 + 255) / 256), dim3(256), 0, stream>>>(Wv, wvb, nW / 4);
    cvt_f32_bf16<<<dim3((nW / 4 + 255) / 256), dim3(256), 0, stream>>>(Wo, wob, nW / 4);

    // projections: Q/K/V = xb @ W^T + b  (output bf16)
    dim3 ggrid(MT / 128, DM / 32);
    gemm_bt<true><<<ggrid, dim3(256), 0, stream>>>(xb, wqb, bq, Qb, MT, DM, DM);
    gemm_bt<true><<<ggrid, dim3(256), 0, stream>>>(xb, wkb, bk, Kb, MT, DM, DM);
    gemm_bt<true><<<ggrid, dim3(256), 0, stream>>>(xb, wvb, bv, Vb, MT, DM, DM);

    // causal MFMA flash attention -> Pb (bf16)
    attn_mfma<<<dim3(BB * NH, S / 128), dim3(256), 0, stream>>>(Qb, Kb, Vb, Pb);

    // output projection: out = Pb @ Wo^T + bo (fp32)
    gemm_bt<false><<<ggrid, dim3(256), 0, stream>>>(Pb, wob, bo, out, MT, DM, DM);
}

// Round 3
// 174.693 us; speedup vs baseline: 16.2244x; 2.2302x over previous
//
#include <hip/hip_runtime.h>

// ---------------------------------------------------------------------------
// MHA block: q,k,v = x@W*.T + b*; causal softmax attention; out = preout@Wo.T+bo
// B=2, S=2048, D=1024, NH=16, HD=64. fp32 I/O, bf16 internal (MFMA everywhere).
// Round 3: m97-structure GEMMs (global_load_lds, 128^2 tile), fused QKV (N=3072),
//          attention 64q blocks, conflict-free d-major V transpose staging.
// ---------------------------------------------------------------------------

#define DEV __device__ __forceinline__

typedef __bf16 bf16x8 __attribute__((ext_vector_type(8)));
typedef float  f32x4  __attribute__((ext_vector_type(4)));
typedef unsigned short u16;
typedef u16 u16x8 __attribute__((ext_vector_type(8)));
typedef u16 u16x4 __attribute__((ext_vector_type(4)));

constexpr int BB  = 2;
constexpr int S   = 2048;
constexpr int DM  = 1024;
constexpr int NH  = 16;
constexpr int MT  = BB * S;      // 4096 token rows
constexpr int LDQ = 3 * DM;      // fused QKV row stride (3072)

DEV u16 f2bf(float f) {
    unsigned u = __float_as_uint(f);
    unsigned r = u + 0x7fffu + ((u >> 16) & 1u);   // RNE
    return (u16)(r >> 16);
}

typedef const __attribute__((address_space(1))) void* gas_t;
typedef __attribute__((address_space(3))) void* las_t;
DEV void gl16(const u16* g, u16* l) {
    __builtin_amdgcn_global_load_lds((gas_t)g, (las_t)l, 16, 0, 0);
}

// ---------------------------------------------------------------------------
// fp32 -> bf16 convert (vectorized x4)
// ---------------------------------------------------------------------------
__global__ void cvt_f32_bf16(const float* __restrict__ in, u16* __restrict__ out, int n4) {
    int i = blockIdx.x * blockDim.x + threadIdx.x;
    if (i < n4) {
        float4 v = reinterpret_cast<const float4*>(in)[i];
        u16x4 o;
        o[0] = f2bf(v.x); o[1] = f2bf(v.y); o[2] = f2bf(v.z); o[3] = f2bf(v.w);
        reinterpret_cast<u16x4*>(out)[i] = o;
    }
}

// ---------------------------------------------------------------------------
// GEMM (m97 structure): C[M x N] = A[M x K](bf16) @ W[N x K]^T(bf16) + bias
// 128x128 block tile, BK=32, 4 waves (2x2), each wave 64x64 (4x4 MFMA frags).
// Staging via global_load_lds width 16 (linear LDS layout, per-lane gsrc).
// Bias selected from 3 segment pointers (fused QKV: 1024-col segments).
// ---------------------------------------------------------------------------
template <bool OUT_BF16>
__global__ __launch_bounds__(256) void gemm_lds(const u16* __restrict__ A,
                                                const u16* __restrict__ W,
                                                const float* __restrict__ b0,
                                                const float* __restrict__ b1,
                                                const float* __restrict__ b2,
                                                void* __restrict__ Cout,
                                                int K, int ldc) {
    __shared__ __align__(16) u16 Al[128 * 32];
    __shared__ __align__(16) u16 Bl[128 * 32];

    const int tid  = threadIdx.x;
    const int lane = tid & 63;
    const int w    = tid >> 6;
    const int ln   = lane & 15;
    const int g    = lane >> 4;
    const int kg8  = g * 8;
    const int wr   = w >> 1, wc = w & 1;
    const int m0   = blockIdx.x * 128, n0 = blockIdx.y * 128;

    const float* bias; int nb;
    if (n0 >= 2048)      { bias = b2; nb = n0 - 2048; }
    else if (n0 >= 1024) { bias = b1; nb = n0 - 1024; }
    else                 { bias = b0; nb = n0; }

    // staging: chunk = it*256 + tid; row = chunk>>2, col8 = (chunk&3)*8
    const int r_  = tid >> 2;
    const int c8_ = (tid & 3) << 3;
    const u16* gA0 = A + (size_t)(m0 + r_) * K + c8_;
    const u16* gA1 = gA0 + (size_t)64 * K;
    const u16* gW0 = W + (size_t)(n0 + r_) * K + c8_;
    const u16* gW1 = gW0 + (size_t)64 * K;
    u16* lA0 = Al + tid * 8;
    u16* lA1 = Al + (256 + tid) * 8;
    u16* lB0 = Bl + tid * 8;
    u16* lB1 = Bl + (256 + tid) * 8;

    f32x4 acc[4][4] = {};

    for (int kb = 0; kb < K; kb += 32) {
        __syncthreads();
        gl16(gA0 + kb, lA0);
        gl16(gA1 + kb, lA1);
        gl16(gW0 + kb, lB0);
        gl16(gW1 + kb, lB1);
        __syncthreads();

        bf16x8 ar[4], br[4];
        #pragma unroll
        for (int i = 0; i < 4; ++i)
            ar[i] = *reinterpret_cast<const bf16x8*>(&Al[(wr * 64 + i * 16 + ln) * 32 + kg8]);
        #pragma unroll
        for (int j = 0; j < 4; ++j)
            br[j] = *reinterpret_cast<const bf16x8*>(&Bl[(wc * 64 + j * 16 + ln) * 32 + kg8]);
        #pragma unroll
        for (int i = 0; i < 4; ++i)
            #pragma unroll
            for (int j = 0; j < 4; ++j)
                acc[i][j] = __builtin_amdgcn_mfma_f32_16x16x32_bf16(ar[i], br[j], acc[i][j], 0, 0, 0);
    }

    float bv[4];
    #pragma unroll
    for (int j = 0; j < 4; ++j) bv[j] = bias[nb + wc * 64 + j * 16 + ln];

    #pragma unroll
    for (int i = 0; i < 4; ++i)
        #pragma unroll
        for (int j = 0; j < 4; ++j) {
            const int col = n0 + wc * 64 + j * 16 + ln;
            #pragma unroll
            for (int r = 0; r < 4; ++r) {
                const int row = m0 + wr * 64 + i * 16 + g * 4 + r;
                const float v = acc[i][j][r] + bv[j];
                if (OUT_BF16)
                    ((u16*)Cout)[(size_t)row * ldc + col] = f2bf(v);
                else
                    ((float*)Cout)[(size_t)row * ldc + col] = v;
            }
        }
}

// ---------------------------------------------------------------------------
// Causal flash attention with MFMA.
// Block: 256 threads = 4 waves, 64 queries of one (b,h); wave w owns 16 queries.
// KV tiles of 64 keys staged in LDS: K natural rows; V transposed d-major
// (lane gathers 8 keys of one dim -> one aligned ds_write_b128, conflict-free).
// Grid y pairs short/long causal chunks for balance.
// ---------------------------------------------------------------------------
__global__ __launch_bounds__(256) void attn_mfma(const u16* __restrict__ QKV,
                                                 u16* __restrict__ Pg) {
    const int bh = blockIdx.x;
    const int b  = bh >> 4, h = bh & 15;
    const int y  = blockIdx.y;
    const int qc = (y & 1) ? (31 - (y >> 1)) : (y >> 1);
    const int q0 = qc * 64;
    const int tid  = threadIdx.x;
    const int w    = tid >> 6;
    const int lane = tid & 63;
    const int ln   = lane & 15;
    const int g    = lane >> 4;
    const int kg8  = g * 8;

    __shared__ __align__(16) u16 Kl[64][72];
    __shared__ __align__(16) u16 Vt[64][72];      // Vt[dim][key]
    __shared__ __align__(16) u16 Pl[4][16][72];   // per-wave P buffer

    // Q fragments: wave w owns queries q0 + w*16 .. +15
    bf16x8 qf[2];
    #pragma unroll
    for (int kk = 0; kk < 2; ++kk)
        qf[kk] = *reinterpret_cast<const bf16x8*>(
            &QKV[(size_t)(b * S + q0 + w * 16 + ln) * LDQ + h * 64 + kk * 32 + kg8]);

    f32x4 o[4] = {};
    float m[4], l[4];
    #pragma unroll
    for (int r = 0; r < 4; ++r) { m[r] = -1e30f; l[r] = 0.0f; }

    const int ntiles = qc + 1;
    for (int t = 0; t < ntiles; ++t) {
        const int j0 = t * 64;
        __syncthreads();
        // ---- stage K tile (key-major rows) ----
        #pragma unroll
        for (int it = 0; it < 2; ++it) {
            const int idx = it * 256 + tid;
            const int r   = idx >> 3;
            const int c8  = (idx & 7) << 3;
            *reinterpret_cast<u16x8*>(&Kl[r][c8]) = *reinterpret_cast<const u16x8*>(
                &QKV[(size_t)(b * S + j0 + r) * LDQ + DM + h * 64 + c8]);
        }
        // ---- stage V transposed, d-major: lane owns (dim d, key-group kg) ----
        #pragma unroll
        for (int it = 0; it < 2; ++it) {
            const int task = it * 256 + tid;
            const int d    = task & 63;
            const int kg   = task >> 6;        // 0..7
            const u16* vsrc = &QKV[(size_t)(b * S + j0 + kg * 8) * LDQ + 2 * DM + h * 64 + d];
            u16x8 tv;
            #pragma unroll
            for (int i = 0; i < 8; ++i) tv[i] = vsrc[(size_t)i * LDQ];
            *reinterpret_cast<u16x8*>(&Vt[d][kg * 8]) = tv;
        }
        __syncthreads();

        // ---- QK^T ----
        f32x4 s[4] = {};
        #pragma unroll
        for (int kk = 0; kk < 2; ++kk)
            #pragma unroll
            for (int c = 0; c < 4; ++c) {
                bf16x8 kf = *reinterpret_cast<const bf16x8*>(&Kl[c * 16 + ln][kk * 32 + kg8]);
                s[c] = __builtin_amdgcn_mfma_f32_16x16x32_bf16(qf[kk], kf, s[c], 0, 0, 0);
            }

        // ---- online softmax (mask only on diagonal tile) ----
        const bool lastt = (t == ntiles - 1);
        const int qb = q0 + w * 16 + g * 4;
        float tm[4];
        #pragma unroll
        for (int r = 0; r < 4; ++r) {
            #pragma unroll
            for (int c = 0; c < 4; ++c) {
                float v = s[c][r] * 0.125f;
                if (lastt && (j0 + c * 16 + ln > qb + r)) v = -1e30f;
                s[c][r] = v;
            }
            tm[r] = fmaxf(fmaxf(s[0][r], s[1][r]), fmaxf(s[2][r], s[3][r]));
        }
        #pragma unroll
        for (int mk = 1; mk <= 8; mk <<= 1)
            #pragma unroll
            for (int r = 0; r < 4; ++r)
                tm[r] = fmaxf(tm[r], __shfl_xor(tm[r], mk, 64));
        float cr[4], ts[4];
        #pragma unroll
        for (int r = 0; r < 4; ++r) {
            const float mn = fmaxf(m[r], tm[r]);
            cr[r] = __expf(m[r] - mn);
            m[r] = mn;
            ts[r] = 0.0f;
            #pragma unroll
            for (int c = 0; c < 4; ++c) {
                const float p = __expf(s[c][r] - mn);
                s[c][r] = p;
                ts[r] += p;
            }
        }
        #pragma unroll
        for (int mk = 1; mk <= 8; mk <<= 1)
            #pragma unroll
            for (int r = 0; r < 4; ++r)
                ts[r] += __shfl_xor(ts[r], mk, 64);
        #pragma unroll
        for (int r = 0; r < 4; ++r)
            l[r] = l[r] * cr[r] + ts[r];
        // P -> per-wave LDS (bf16)
        #pragma unroll
        for (int c = 0; c < 4; ++c)
            #pragma unroll
            for (int r = 0; r < 4; ++r)
                Pl[w][g * 4 + r][c * 16 + ln] = f2bf(s[c][r]);
        // rescale O
        #pragma unroll
        for (int d = 0; d < 4; ++d)
            #pragma unroll
            for (int r = 0; r < 4; ++r)
                o[d][r] *= cr[r];

        // ---- PV ----
        #pragma unroll
        for (int kk = 0; kk < 2; ++kk) {
            bf16x8 pf = *reinterpret_cast<const bf16x8*>(&Pl[w][ln][kk * 32 + kg8]);
            #pragma unroll
            for (int d = 0; d < 4; ++d) {
                bf16x8 vf = *reinterpret_cast<const bf16x8*>(&Vt[d * 16 + ln][kk * 32 + kg8]);
                o[d] = __builtin_amdgcn_mfma_f32_16x16x32_bf16(pf, vf, o[d], 0, 0, 0);
            }
        }
    }

    // ---- epilogue ----
    float inv[4];
    #pragma unroll
    for (int r = 0; r < 4; ++r) inv[r] = 1.0f / l[r];
    #pragma unroll
    for (int d = 0; d < 4; ++d)
        #pragma unroll
        for (int r = 0; r < 4; ++r) {
            const int q = q0 + w * 16 + g * 4 + r;
            Pg[(size_t)(b * S + q) * DM + h * 64 + d * 16 + ln] = f2bf(o[d][r] * inv[r]);
        }
}

// ---------------------------------------------------------------------------
// launch
// ---------------------------------------------------------------------------
extern "C" void kernel_launch(void* const* d_in, const int* in_sizes, int n_in,
                              void* d_out, int out_size, void* d_ws, size_t ws_size,
                              hipStream_t stream) {
    const float* x  = (const float*)d_in[0];
    const float* Wq = (const float*)d_in[1];
    const float* bq = (const float*)d_in[2];
    const float* Wk = (const float*)d_in[3];
    const float* bk = (const float*)d_in[4];
    const float* Wv = (const float*)d_in[5];
    const float* bv = (const float*)d_in[6];
    const float* Wo = (const float*)d_in[7];
    const float* bo = (const float*)d_in[8];
    float* out = (float*)d_out;

    // workspace layout (all bf16 = u16): 24M elems = 48 MB
    u16* xb   = (u16*)d_ws;                      // MT*DM
    u16* wqb  = xb   + (size_t)MT * DM;          // DM*DM  } contiguous ->
    u16* wkb  = wqb  + (size_t)DM * DM;          // DM*DM  } fused W_qkv
    u16* wvb  = wkb  + (size_t)DM * DM;          // DM*DM  } [3072][1024]
    u16* wob  = wvb  + (size_t)DM * DM;
    u16* QKVb = wob  + (size_t)DM * DM;          // MT*3DM
    u16* Pb   = QKVb + (size_t)MT * 3 * DM;      // MT*DM

    const int nX = MT * DM;
    const int nW = DM * DM;

    // converts
    cvt_f32_bf16<<<dim3((nX / 4 + 255) / 256), dim3(256), 0, stream>>>(x,  xb,  nX / 4);
    cvt_f32_bf16<<<dim3((nW / 4 + 255) / 256), dim3(256), 0, stream>>>(Wq, wqb, nW / 4);
    cvt_f32_bf16<<<dim3((nW / 4 + 255) / 256), dim3(256), 0, stream>>>(Wk, wkb, nW / 4);
    cvt_f32_bf16<<<dim3((nW / 4 + 255) / 256), dim3(256), 0, stream>>>(Wv, wvb, nW / 4);
    cvt_f32_bf16<<<dim3((nW / 4 + 255) / 256), dim3(256), 0, stream>>>(Wo, wob, nW / 4);

    // fused QKV projection: [4096 x 3072] = xb @ Wqkv^T + [bq|bk|bv]
    gemm_lds<true><<<dim3(MT / 128, 3 * DM / 128), dim3(256), 0, stream>>>(
        xb, wqb, bq, bk, bv, QKVb, DM, LDQ);

    // causal MFMA flash attention -> Pb (bf16)
    attn_mfma<<<dim3(BB * NH, S / 64), dim3(256), 0, stream>>>(QKVb, Pb);

    // output projection: out = Pb @ Wo^T + bo (fp32)
    gemm_lds<false><<<dim3(MT / 128, DM / 128), dim3(256), 0, stream>>>(
        Pb, wob, bo, bo, bo, out, DM, DM);
}

// Round 4
// 164.845 us; speedup vs baseline: 17.1937x; 1.0597x over previous
//
#include <hip/hip_runtime.h>

// ---------------------------------------------------------------------------
// MHA block: q,k,v = x@W*.T + b*; causal softmax attention; out = preout@Wo.T+bo
// B=2, S=2048, D=1024, NH=16, HD=64. fp32 I/O, bf16 internal (MFMA everywhere).
// Round 4: pre-transposed V (global), gl16-staged K/Vt with XOR swizzle via
//          pre-swizzled global source, double-buffered tiles w/ counted vmcnt,
//          conflict-free P buffer, exp2 softmax with scale folded into Q.
// ---------------------------------------------------------------------------

#define DEV __device__ __forceinline__

typedef __bf16 bf16x8 __attribute__((ext_vector_type(8)));
typedef float  f32x4  __attribute__((ext_vector_type(4)));
typedef unsigned short u16;
typedef u16 u16x8 __attribute__((ext_vector_type(8)));
typedef u16 u16x4 __attribute__((ext_vector_type(4)));

constexpr int BB  = 2;
constexpr int S   = 2048;
constexpr int DM  = 1024;
constexpr int NH  = 16;
constexpr int MT  = BB * S;      // 4096 token rows
constexpr int LDQ = 3 * DM;      // fused QKV row stride (3072)

DEV u16 f2bf(float f) {
    unsigned u = __float_as_uint(f);
    unsigned r = u + 0x7fffu + ((u >> 16) & 1u);   // RNE
    return (u16)(r >> 16);
}

typedef const __attribute__((address_space(1))) void* gas_t;
typedef __attribute__((address_space(3))) void* las_t;
DEV void gl16(const u16* g, u16* l) {
    __builtin_amdgcn_global_load_lds((gas_t)g, (las_t)l, 16, 0, 0);
}

// ---------------------------------------------------------------------------
// fp32 -> bf16 convert (vectorized x4)
// ---------------------------------------------------------------------------
__global__ void cvt_f32_bf16(const float* __restrict__ in, u16* __restrict__ out, int n4) {
    int i = blockIdx.x * blockDim.x + threadIdx.x;
    if (i < n4) {
        float4 v = reinterpret_cast<const float4*>(in)[i];
        u16x4 o;
        o[0] = f2bf(v.x); o[1] = f2bf(v.y); o[2] = f2bf(v.z); o[3] = f2bf(v.w);
        reinterpret_cast<u16x4*>(out)[i] = o;
    }
}

// ---------------------------------------------------------------------------
// GEMM (m97 structure): C[M x N] = A[M x K](bf16) @ W[N x K]^T(bf16) + bias,
// then * segment scale. 128x128 tile, BK=32, 4 waves, global_load_lds staging.
// ---------------------------------------------------------------------------
template <bool OUT_BF16>
__global__ __launch_bounds__(256) void gemm_lds(const u16* __restrict__ A,
                                                const u16* __restrict__ W,
                                                const float* __restrict__ b0,
                                                const float* __restrict__ b1,
                                                const float* __restrict__ b2,
                                                float sc0, float sc1, float sc2,
                                                void* __restrict__ Cout,
                                                int K, int ldc) {
    __shared__ __align__(16) u16 Al[128 * 32];
    __shared__ __align__(16) u16 Bl[128 * 32];

    const int tid  = threadIdx.x;
    const int lane = tid & 63;
    const int w    = tid >> 6;
    const int ln   = lane & 15;
    const int g    = lane >> 4;
    const int kg8  = g * 8;
    const int wr   = w >> 1, wc = w & 1;
    const int m0   = blockIdx.x * 128, n0 = blockIdx.y * 128;

    const float* bias; int nb; float scl;
    if (n0 >= 2048)      { bias = b2; nb = n0 - 2048; scl = sc2; }
    else if (n0 >= 1024) { bias = b1; nb = n0 - 1024; scl = sc1; }
    else                 { bias = b0; nb = n0;        scl = sc0; }

    const int r_  = tid >> 2;
    const int c8_ = (tid & 3) << 3;
    const u16* gA0 = A + (size_t)(m0 + r_) * K + c8_;
    const u16* gA1 = gA0 + (size_t)64 * K;
    const u16* gW0 = W + (size_t)(n0 + r_) * K + c8_;
    const u16* gW1 = gW0 + (size_t)64 * K;
    u16* lA0 = Al + tid * 8;
    u16* lA1 = Al + (256 + tid) * 8;
    u16* lB0 = Bl + tid * 8;
    u16* lB1 = Bl + (256 + tid) * 8;

    f32x4 acc[4][4] = {};

    for (int kb = 0; kb < K; kb += 32) {
        __syncthreads();
        gl16(gA0 + kb, lA0);
        gl16(gA1 + kb, lA1);
        gl16(gW0 + kb, lB0);
        gl16(gW1 + kb, lB1);
        __syncthreads();

        bf16x8 ar[4], br[4];
        #pragma unroll
        for (int i = 0; i < 4; ++i)
            ar[i] = *reinterpret_cast<const bf16x8*>(&Al[(wr * 64 + i * 16 + ln) * 32 + kg8]);
        #pragma unroll
        for (int j = 0; j < 4; ++j)
            br[j] = *reinterpret_cast<const bf16x8*>(&Bl[(wc * 64 + j * 16 + ln) * 32 + kg8]);
        #pragma unroll
        for (int i = 0; i < 4; ++i)
            #pragma unroll
            for (int j = 0; j < 4; ++j)
                acc[i][j] = __builtin_amdgcn_mfma_f32_16x16x32_bf16(ar[i], br[j], acc[i][j], 0, 0, 0);
    }

    float bv[4];
    #pragma unroll
    for (int j = 0; j < 4; ++j) bv[j] = bias[nb + wc * 64 + j * 16 + ln];

    #pragma unroll
    for (int i = 0; i < 4; ++i)
        #pragma unroll
        for (int j = 0; j < 4; ++j) {
            const int col = n0 + wc * 64 + j * 16 + ln;
            #pragma unroll
            for (int r = 0; r < 4; ++r) {
                const int row = m0 + wr * 64 + i * 16 + g * 4 + r;
                const float v = (acc[i][j][r] + bv[j]) * scl;
                if (OUT_BF16)
                    ((u16*)Cout)[(size_t)row * ldc + col] = f2bf(v);
                else
                    ((float*)Cout)[(size_t)row * ldc + col] = v;
            }
        }
}

// ---------------------------------------------------------------------------
// V transpose: QKV V-segment -> Vtg[bh][d][S] (bf16), LDS-tiled, coalesced.
// ---------------------------------------------------------------------------
__global__ __launch_bounds__(256) void transpose_v(const u16* __restrict__ QKV,
                                                   u16* __restrict__ Vtg) {
    const int bh = blockIdx.x;
    const int b  = bh >> 4, h = bh & 15;
    const int j0 = blockIdx.y * 64;
    const int tid = threadIdx.x;
    __shared__ __align__(16) u16 Vl[64][72];
    #pragma unroll
    for (int it = 0; it < 2; ++it) {
        const int idx = it * 256 + tid;
        const int r = idx >> 3, c8 = (idx & 7) << 3;
        *reinterpret_cast<u16x8*>(&Vl[r][c8]) = *reinterpret_cast<const u16x8*>(
            &QKV[(size_t)(b * S + j0 + r) * LDQ + 2 * DM + h * 64 + c8]);
    }
    __syncthreads();
    #pragma unroll
    for (int it = 0; it < 2; ++it) {
        const int idx = it * 256 + tid;
        const int d = idx >> 3, k8 = (idx & 7) << 3;
        u16x8 o;
        #pragma unroll
        for (int i = 0; i < 8; ++i) o[i] = Vl[k8 + i][d];
        *reinterpret_cast<u16x8*>(&Vtg[(size_t)(bh * 64 + d) * S + j0 + k8]) = o;
    }
}

// ---------------------------------------------------------------------------
// Causal flash attention with MFMA.
// 256 thr = 4 waves, 64 queries/block (wave owns 16). 64-key tiles.
// K and Vt staged via global_load_lds (linear LDS [64][64]) with XOR bank
// swizzle applied by pre-swizzling the per-lane GLOBAL source chunk; frag
// reads apply the same XOR. Double-buffered with counted vmcnt(4).
// Q pre-scaled by 0.125*log2(e) in the QKV GEMM -> softmax uses exp2.
// ---------------------------------------------------------------------------
__global__ __launch_bounds__(256) void attn_mfma(const u16* __restrict__ QKV,
                                                 const u16* __restrict__ Vtg,
                                                 u16* __restrict__ Pg) {
    const int bh = blockIdx.x;
    const int b  = bh >> 4, h = bh & 15;
    const int y  = blockIdx.y;
    const int qc = (y & 1) ? (31 - (y >> 1)) : (y >> 1);
    const int q0 = qc * 64;
    const int tid  = threadIdx.x;
    const int w    = tid >> 6;
    const int lane = tid & 63;
    const int ln   = lane & 15;
    const int g    = lane >> 4;
    const int kg8  = g * 8;
    const int l7   = ln & 7;

    __shared__ __align__(16) u16 Kbuf[2][64 * 64];
    __shared__ __align__(16) u16 Vbuf[2][64 * 64];
    __shared__ __align__(16) u16 Pl[4][16][68];

    // staging geometry: chunk C = it*256+tid; row r = C>>3; stored slot = tid&7;
    // global chunk fetched = slot ^ (r&7)  (involution -> read applies same XOR)
    const int slot = tid & 7;
    const int r0   = tid >> 3;                   // rows 0..31 (it=0), +32 (it=1)
    const size_t kRowBase = (size_t)(b * S) * LDQ + DM + h * 64;
    const size_t vRowBase = (size_t)(bh * 64) * S;

    // Q fragments: wave w owns queries q0 + w*16 .. +15 (already scaled)
    bf16x8 qf[2];
    #pragma unroll
    for (int kk = 0; kk < 2; ++kk)
        qf[kk] = *reinterpret_cast<const bf16x8*>(
            &QKV[(size_t)(b * S + q0 + w * 16 + ln) * LDQ + h * 64 + kk * 32 + kg8]);

    f32x4 o[4] = {};
    float m[4], l[4];
    #pragma unroll
    for (int r = 0; r < 4; ++r) { m[r] = -1e30f; l[r] = 0.0f; }

    const int ntiles = qc + 1;

    // ---- stage tile 0 into buf 0 ----
    {
        const int xr0 = (slot ^ (r0 & 7)) << 3;
        gl16(&QKV[kRowBase + (size_t)(0 + r0) * LDQ + xr0],            &Kbuf[0][tid * 8]);
        gl16(&QKV[kRowBase + (size_t)(32 + r0) * LDQ + xr0],           &Kbuf[0][2048 + tid * 8]);
        gl16(&Vtg[vRowBase + (size_t)r0 * S + 0 + xr0],                &Vbuf[0][tid * 8]);
        gl16(&Vtg[vRowBase + (size_t)(32 + r0) * S + 0 + xr0],         &Vbuf[0][2048 + tid * 8]);
    }

    int cur = 0;
    for (int t = 0; t < ntiles; ++t) {
        const int j0 = t * 64;
        const bool more = (t + 1 < ntiles);
        if (more) {
            const int jn = j0 + 64;
            const int xr0 = (slot ^ (r0 & 7)) << 3;
            u16* kb = &Kbuf[cur ^ 1][0];
            u16* vb = &Vbuf[cur ^ 1][0];
            gl16(&QKV[kRowBase + (size_t)(jn + r0) * LDQ + xr0],      kb + tid * 8);
            gl16(&QKV[kRowBase + (size_t)(jn + 32 + r0) * LDQ + xr0], kb + 2048 + tid * 8);
            gl16(&Vtg[vRowBase + (size_t)r0 * S + jn + xr0],          vb + tid * 8);
            gl16(&Vtg[vRowBase + (size_t)(32 + r0) * S + jn + xr0],   vb + 2048 + tid * 8);
            asm volatile("s_waitcnt vmcnt(4)" ::: "memory");
        } else {
            asm volatile("s_waitcnt vmcnt(0)" ::: "memory");
        }
        __syncthreads();

        const u16* Kb = &Kbuf[cur][0];
        const u16* Vb = &Vbuf[cur][0];

        // ---- QK^T (logits already in log2 units) ----
        f32x4 s[4] = {};
        #pragma unroll
        for (int kk = 0; kk < 2; ++kk)
            #pragma unroll
            for (int c = 0; c < 4; ++c) {
                bf16x8 kf = *reinterpret_cast<const bf16x8*>(
                    &Kb[(c * 16 + ln) * 64 + (((kk * 4 + g) ^ l7) << 3)]);
                s[c] = __builtin_amdgcn_mfma_f32_16x16x32_bf16(qf[kk], kf, s[c], 0, 0, 0);
            }

        // ---- causal mask (diagonal tile only) ----
        if (t == ntiles - 1) {
            const int qb = q0 + w * 16 + g * 4;
            #pragma unroll
            for (int c = 0; c < 4; ++c)
                #pragma unroll
                for (int r = 0; r < 4; ++r)
                    if (j0 + c * 16 + ln > qb + r) s[c][r] = -1e30f;
        }

        // ---- online softmax (exp2 domain) ----
        float tm[4];
        #pragma unroll
        for (int r = 0; r < 4; ++r)
            tm[r] = fmaxf(fmaxf(s[0][r], s[1][r]), fmaxf(s[2][r], s[3][r]));
        #pragma unroll
        for (int mk = 1; mk <= 8; mk <<= 1)
            #pragma unroll
            for (int r = 0; r < 4; ++r)
                tm[r] = fmaxf(tm[r], __shfl_xor(tm[r], mk, 64));
        float cr[4], ts[4];
        #pragma unroll
        for (int r = 0; r < 4; ++r) {
            const float mn = fmaxf(m[r], tm[r]);
            cr[r] = exp2f(m[r] - mn);
            m[r] = mn;
            ts[r] = 0.0f;
            #pragma unroll
            for (int c = 0; c < 4; ++c) {
                const float p = exp2f(s[c][r] - mn);
                s[c][r] = p;
                ts[r] += p;
            }
        }
        #pragma unroll
        for (int mk = 1; mk <= 8; mk <<= 1)
            #pragma unroll
            for (int r = 0; r < 4; ++r)
                ts[r] += __shfl_xor(ts[r], mk, 64);
        #pragma unroll
        for (int r = 0; r < 4; ++r)
            l[r] = l[r] * cr[r] + ts[r];
        // P -> per-wave LDS (bf16), conflict-free (LD=68)
        #pragma unroll
        for (int c = 0; c < 4; ++c)
            #pragma unroll
            for (int r = 0; r < 4; ++r)
                Pl[w][g * 4 + r][c * 16 + ln] = f2bf(s[c][r]);
        // rescale O
        #pragma unroll
        for (int d = 0; d < 4; ++d)
            #pragma unroll
            for (int r = 0; r < 4; ++r)
                o[d][r] *= cr[r];

        // ---- PV ----
        #pragma unroll
        for (int kk = 0; kk < 2; ++kk) {
            bf16x8 pf = *reinterpret_cast<const bf16x8*>(&Pl[w][ln][kk * 32 + kg8]);
            #pragma unroll
            for (int d = 0; d < 4; ++d) {
                bf16x8 vf = *reinterpret_cast<const bf16x8*>(
                    &Vb[(d * 16 + ln) * 64 + (((kk * 4 + g) ^ l7) << 3)]);
                o[d] = __builtin_amdgcn_mfma_f32_16x16x32_bf16(pf, vf, o[d], 0, 0, 0);
            }
        }
        __syncthreads();
        cur ^= 1;
    }

    // ---- epilogue ----
    float inv[4];
    #pragma unroll
    for (int r = 0; r < 4; ++r) inv[r] = 1.0f / l[r];
    #pragma unroll
    for (int d = 0; d < 4; ++d)
        #pragma unroll
        for (int r = 0; r < 4; ++r) {
            const int q = q0 + w * 16 + g * 4 + r;
            Pg[(size_t)(b * S + q) * DM + h * 64 + d * 16 + ln] = f2bf(o[d][r] * inv[r]);
        }
}

// ---------------------------------------------------------------------------
// launch
// ---------------------------------------------------------------------------
extern "C" void kernel_launch(void* const* d_in, const int* in_sizes, int n_in,
                              void* d_out, int out_size, void* d_ws, size_t ws_size,
                              hipStream_t stream) {
    const float* x  = (const float*)d_in[0];
    const float* Wq = (const float*)d_in[1];
    const float* bq = (const float*)d_in[2];
    const float* Wk = (const float*)d_in[3];
    const float* bk = (const float*)d_in[4];
    const float* Wv = (const float*)d_in[5];
    const float* bv = (const float*)d_in[6];
    const float* Wo = (const float*)d_in[7];
    const float* bo = (const float*)d_in[8];
    float* out = (float*)d_out;

    // workspace (u16 elems): xb 4M (reused as Pb) | W's 4x1M | QKV 12M | Vtg 4M
    u16* xb   = (u16*)d_ws;                      // MT*DM ; later aliased as Pb
    u16* wqb  = xb   + (size_t)MT * DM;
    u16* wkb  = wqb  + (size_t)DM * DM;
    u16* wvb  = wkb  + (size_t)DM * DM;
    u16* wob  = wvb  + (size_t)DM * DM;
    u16* QKVb = wob  + (size_t)DM * DM;          // MT*3DM
    u16* Vtg  = QKVb + (size_t)MT * 3 * DM;      // MT*DM  (32 bh * 64 d * 2048)
    u16* Pb   = xb;                              // alias: x no longer needed

    const int nX = MT * DM;
    const int nW = DM * DM;

    // converts
    cvt_f32_bf16<<<dim3((nX / 4 + 255) / 256), dim3(256), 0, stream>>>(x,  xb,  nX / 4);
    cvt_f32_bf16<<<dim3((nW / 4 + 255) / 256), dim3(256), 0, stream>>>(Wq, wqb, nW / 4);
    cvt_f32_bf16<<<dim3((nW / 4 + 255) / 256), dim3(256), 0, stream>>>(Wk, wkb, nW / 4);
    cvt_f32_bf16<<<dim3((nW / 4 + 255) / 256), dim3(256), 0, stream>>>(Wv, wvb, nW / 4);
    cvt_f32_bf16<<<dim3((nW / 4 + 255) / 256), dim3(256), 0, stream>>>(Wo, wob, nW / 4);

    // fused QKV projection; Q segment scaled by 0.125*log2(e) for exp2 softmax
    const float SCL = 0.125f * 1.4426950408889634f;
    gemm_lds<true><<<dim3(MT / 128, 3 * DM / 128), dim3(256), 0, stream>>>(
        xb, wqb, bq, bk, bv, SCL, 1.0f, 1.0f, QKVb, DM, LDQ);

    // V transpose -> Vtg[bh][d][S]
    transpose_v<<<dim3(BB * NH, S / 64), dim3(256), 0, stream>>>(QKVb, Vtg);

    // causal MFMA flash attention -> Pb (bf16)
    attn_mfma<<<dim3(BB * NH, S / 64), dim3(256), 0, stream>>>(QKVb, Vtg, Pb);

    // output projection: out = Pb @ Wo^T + bo (fp32)
    gemm_lds<false><<<dim3(MT / 128, DM / 128), dim3(256), 0, stream>>>(
        Pb, wob, bo, bo, bo, 1.0f, 1.0f, 1.0f, out, DM, DM);
}

// Round 5
// 138.515 us; speedup vs baseline: 20.4621x; 1.1901x over previous
//
#include <hip/hip_runtime.h>

// ---------------------------------------------------------------------------
// MHA block: q,k,v = x@W*.T + b*; causal softmax attention; out = preout@Wo.T+bo
// B=2, S=2048, D=1024, NH=16, HD=64. fp32 I/O, bf16 internal (MFMA everywhere).
// Round 5: swapped QK^T (mfma(K,Q)) -> per-lane-query softmax (2 shfl reduce),
//          cvt_pk P conversion + b64 P writes, setprio around MFMA,
//          2-phase double-buffered GEMM staging with counted vmcnt.
// ---------------------------------------------------------------------------

#define DEV __device__ __forceinline__

typedef __bf16 bf16x8 __attribute__((ext_vector_type(8)));
typedef float  f32x4  __attribute__((ext_vector_type(4)));
typedef unsigned short u16;
typedef u16 u16x8 __attribute__((ext_vector_type(8)));
typedef u16 u16x4 __attribute__((ext_vector_type(4)));

constexpr int BB  = 2;
constexpr int S   = 2048;
constexpr int DM  = 1024;
constexpr int NH  = 16;
constexpr int MT  = BB * S;      // 4096 token rows
constexpr int LDQ = 3 * DM;      // fused QKV row stride (3072)

DEV u16 f2bf(float f) {
    unsigned u = __float_as_uint(f);
    unsigned r = u + 0x7fffu + ((u >> 16) & 1u);   // RNE
    return (u16)(r >> 16);
}

DEV unsigned cvt_pk_bf16(float lo, float hi) {
    unsigned r;
    asm("v_cvt_pk_bf16_f32 %0, %1, %2" : "=v"(r) : "v"(lo), "v"(hi));
    return r;
}

typedef const __attribute__((address_space(1))) void* gas_t;
typedef __attribute__((address_space(3))) void* las_t;
DEV void gl16(const u16* g, u16* l) {
    __builtin_amdgcn_global_load_lds((gas_t)g, (las_t)l, 16, 0, 0);
}

// ---------------------------------------------------------------------------
// fp32 -> bf16 convert (vectorized x4)
// ---------------------------------------------------------------------------
__global__ void cvt_f32_bf16(const float* __restrict__ in, u16* __restrict__ out, int n4) {
    int i = blockIdx.x * blockDim.x + threadIdx.x;
    if (i < n4) {
        float4 v = reinterpret_cast<const float4*>(in)[i];
        u16x4 o;
        o[0] = f2bf(v.x); o[1] = f2bf(v.y); o[2] = f2bf(v.z); o[3] = f2bf(v.w);
        reinterpret_cast<u16x4*>(out)[i] = o;
    }
}

// ---------------------------------------------------------------------------
// GEMM (m97 structure + 2-phase dbuf): C = A @ W^T + bias, * segment scale.
// 128x128 tile, BK=32, 4 waves; global_load_lds staging overlapped with MFMA.
// ---------------------------------------------------------------------------
template <bool OUT_BF16>
__global__ __launch_bounds__(256) void gemm_lds(const u16* __restrict__ A,
                                                const u16* __restrict__ W,
                                                const float* __restrict__ b0,
                                                const float* __restrict__ b1,
                                                const float* __restrict__ b2,
                                                float sc0, float sc1, float sc2,
                                                void* __restrict__ Cout,
                                                int K, int ldc) {
    __shared__ __align__(16) u16 Al[2][128 * 32];
    __shared__ __align__(16) u16 Bl[2][128 * 32];

    const int tid  = threadIdx.x;
    const int lane = tid & 63;
    const int w    = tid >> 6;
    const int ln   = lane & 15;
    const int g    = lane >> 4;
    const int kg8  = g * 8;
    const int wr   = w >> 1, wc = w & 1;
    const int m0   = blockIdx.x * 128, n0 = blockIdx.y * 128;

    const float* bias; int nb; float scl;
    if (n0 >= 2048)      { bias = b2; nb = n0 - 2048; scl = sc2; }
    else if (n0 >= 1024) { bias = b1; nb = n0 - 1024; scl = sc1; }
    else                 { bias = b0; nb = n0;        scl = sc0; }

    const int r_  = tid >> 2;
    const int c8_ = (tid & 3) << 3;
    const u16* gA0 = A + (size_t)(m0 + r_) * K + c8_;
    const u16* gA1 = gA0 + (size_t)64 * K;
    const u16* gW0 = W + (size_t)(n0 + r_) * K + c8_;
    const u16* gW1 = gW0 + (size_t)64 * K;

    f32x4 acc[4][4] = {};

    // prologue: stage k-tile 0 into buf 0
    gl16(gA0, &Al[0][tid * 8]);
    gl16(gA1, &Al[0][2048 + tid * 8]);
    gl16(gW0, &Bl[0][tid * 8]);
    gl16(gW1, &Bl[0][2048 + tid * 8]);

    int cur = 0;
    for (int kb = 0; kb < K; kb += 32) {
        const bool more = (kb + 32 < K);
        if (more) {
            u16* a = &Al[cur ^ 1][0];
            u16* b = &Bl[cur ^ 1][0];
            gl16(gA0 + kb + 32, a + tid * 8);
            gl16(gA1 + kb + 32, a + 2048 + tid * 8);
            gl16(gW0 + kb + 32, b + tid * 8);
            gl16(gW1 + kb + 32, b + 2048 + tid * 8);
            asm volatile("s_waitcnt vmcnt(4)" ::: "memory");
        } else {
            asm volatile("s_waitcnt vmcnt(0)" ::: "memory");
        }
        __syncthreads();

        bf16x8 ar[4], br[4];
        #pragma unroll
        for (int i = 0; i < 4; ++i)
            ar[i] = *reinterpret_cast<const bf16x8*>(&Al[cur][(wr * 64 + i * 16 + ln) * 32 + kg8]);
        #pragma unroll
        for (int j = 0; j < 4; ++j)
            br[j] = *reinterpret_cast<const bf16x8*>(&Bl[cur][(wc * 64 + j * 16 + ln) * 32 + kg8]);
        #pragma unroll
        for (int i = 0; i < 4; ++i)
            #pragma unroll
            for (int j = 0; j < 4; ++j)
                acc[i][j] = __builtin_amdgcn_mfma_f32_16x16x32_bf16(ar[i], br[j], acc[i][j], 0, 0, 0);
        __syncthreads();
        cur ^= 1;
    }

    float bv[4];
    #pragma unroll
    for (int j = 0; j < 4; ++j) bv[j] = bias[nb + wc * 64 + j * 16 + ln];

    #pragma unroll
    for (int i = 0; i < 4; ++i)
        #pragma unroll
        for (int j = 0; j < 4; ++j) {
            const int col = n0 + wc * 64 + j * 16 + ln;
            #pragma unroll
            for (int r = 0; r < 4; ++r) {
                const int row = m0 + wr * 64 + i * 16 + g * 4 + r;
                const float v = (acc[i][j][r] + bv[j]) * scl;
                if (OUT_BF16)
                    ((u16*)Cout)[(size_t)row * ldc + col] = f2bf(v);
                else
                    ((float*)Cout)[(size_t)row * ldc + col] = v;
            }
        }
}

// ---------------------------------------------------------------------------
// V transpose: QKV V-segment -> Vtg[bh][d][S] (bf16), LDS-tiled, coalesced.
// ---------------------------------------------------------------------------
__global__ __launch_bounds__(256) void transpose_v(const u16* __restrict__ QKV,
                                                   u16* __restrict__ Vtg) {
    const int bh = blockIdx.x;
    const int b  = bh >> 4, h = bh & 15;
    const int j0 = blockIdx.y * 64;
    const int tid = threadIdx.x;
    __shared__ __align__(16) u16 Vl[64][72];
    #pragma unroll
    for (int it = 0; it < 2; ++it) {
        const int idx = it * 256 + tid;
        const int r = idx >> 3, c8 = (idx & 7) << 3;
        *reinterpret_cast<u16x8*>(&Vl[r][c8]) = *reinterpret_cast<const u16x8*>(
            &QKV[(size_t)(b * S + j0 + r) * LDQ + 2 * DM + h * 64 + c8]);
    }
    __syncthreads();
    #pragma unroll
    for (int it = 0; it < 2; ++it) {
        const int idx = it * 256 + tid;
        const int d = idx >> 3, k8 = (idx & 7) << 3;
        u16x8 o;
        #pragma unroll
        for (int i = 0; i < 8; ++i) o[i] = Vl[k8 + i][d];
        *reinterpret_cast<u16x8*>(&Vtg[(size_t)(bh * 64 + d) * S + j0 + k8]) = o;
    }
}

// ---------------------------------------------------------------------------
// Causal flash attention, swapped-QK^T MFMA.
// 256 thr = 4 waves, 64 queries/block (wave owns 16; lane owns query ln).
// QK^T = mfma(Kfrag, Qfrag): C[row=key g*4+r (+16c)][col=query ln] -> softmax
// is per-lane over 16 regs + 2 shfl_xor (cross-g). P packed via cvt_pk,
// written as b64 runs of 4 keys. PV via per-wave Pl + pre-transposed Vt.
// gl16 staging, XOR bank swizzle via pre-swizzled global source, dbuf+vmcnt(4).
// Q pre-scaled by 0.125*log2(e) -> exp2 softmax.
// ---------------------------------------------------------------------------
__global__ __launch_bounds__(256) void attn_mfma(const u16* __restrict__ QKV,
                                                 const u16* __restrict__ Vtg,
                                                 u16* __restrict__ Pg) {
    const int bh = blockIdx.x;
    const int b  = bh >> 4, h = bh & 15;
    const int y  = blockIdx.y;
    const int qc = (y & 1) ? (31 - (y >> 1)) : (y >> 1);
    const int q0 = qc * 64;
    const int tid  = threadIdx.x;
    const int w    = tid >> 6;
    const int lane = tid & 63;
    const int ln   = lane & 15;
    const int g    = lane >> 4;
    const int kg8  = g * 8;
    const int l7   = ln & 7;

    __shared__ __align__(16) u16 Kbuf[2][64 * 64];
    __shared__ __align__(16) u16 Vbuf[2][64 * 64];
    __shared__ __align__(16) u16 Pl[4][16][68];

    const int slot = tid & 7;
    const int r0   = tid >> 3;
    const size_t kRowBase = (size_t)(b * S) * LDQ + DM + h * 64;
    const size_t vRowBase = (size_t)(bh * 64) * S;

    // Q fragments (B operand): lane's query = q0 + w*16 + ln (pre-scaled)
    bf16x8 qf[2];
    #pragma unroll
    for (int kk = 0; kk < 2; ++kk)
        qf[kk] = *reinterpret_cast<const bf16x8*>(
            &QKV[(size_t)(b * S + q0 + w * 16 + ln) * LDQ + h * 64 + kk * 32 + kg8]);

    f32x4 o[4] = {};
    float m = -1e30f, l = 0.0f;     // per-lane: softmax state of query ln

    const int ntiles = qc + 1;

    // ---- stage tile 0 into buf 0 ----
    {
        const int xr0 = (slot ^ (r0 & 7)) << 3;
        gl16(&QKV[kRowBase + (size_t)r0 * LDQ + xr0],          &Kbuf[0][tid * 8]);
        gl16(&QKV[kRowBase + (size_t)(32 + r0) * LDQ + xr0],   &Kbuf[0][2048 + tid * 8]);
        gl16(&Vtg[vRowBase + (size_t)r0 * S + xr0],            &Vbuf[0][tid * 8]);
        gl16(&Vtg[vRowBase + (size_t)(32 + r0) * S + xr0],     &Vbuf[0][2048 + tid * 8]);
    }

    int cur = 0;
    for (int t = 0; t < ntiles; ++t) {
        const bool more = (t + 1 < ntiles);
        if (more) {
            const int jn = (t + 1) * 64;
            const int xr0 = (slot ^ (r0 & 7)) << 3;
            u16* kb = &Kbuf[cur ^ 1][0];
            u16* vb = &Vbuf[cur ^ 1][0];
            gl16(&QKV[kRowBase + (size_t)(jn + r0) * LDQ + xr0],      kb + tid * 8);
            gl16(&QKV[kRowBase + (size_t)(jn + 32 + r0) * LDQ + xr0], kb + 2048 + tid * 8);
            gl16(&Vtg[vRowBase + (size_t)r0 * S + jn + xr0],          vb + tid * 8);
            gl16(&Vtg[vRowBase + (size_t)(32 + r0) * S + jn + xr0],   vb + 2048 + tid * 8);
            asm volatile("s_waitcnt vmcnt(4)" ::: "memory");
        } else {
            asm volatile("s_waitcnt vmcnt(0)" ::: "memory");
        }
        __syncthreads();

        const u16* Kb = &Kbuf[cur][0];
        const u16* Vb = &Vbuf[cur][0];

        // ---- QK^T swapped: s[c] reg r -> key c*16+g*4+r, query ln ----
        f32x4 s[4] = {};
        __builtin_amdgcn_s_setprio(1);
        #pragma unroll
        for (int kk = 0; kk < 2; ++kk)
            #pragma unroll
            for (int c = 0; c < 4; ++c) {
                bf16x8 kf = *reinterpret_cast<const bf16x8*>(
                    &Kb[(c * 16 + ln) * 64 + (((kk * 4 + g) ^ l7) << 3)]);
                s[c] = __builtin_amdgcn_mfma_f32_16x16x32_bf16(kf, qf[kk], s[c], 0, 0, 0);
            }
        __builtin_amdgcn_s_setprio(0);

        // ---- causal mask (diagonal tile only): key > query ----
        if (t == ntiles - 1) {
            const int dq = w * 16 + ln - g * 4;   // mask if c*16 + r > dq
            #pragma unroll
            for (int c = 0; c < 4; ++c)
                #pragma unroll
                for (int r = 0; r < 4; ++r)
                    if (c * 16 + r > dq) s[c][r] = -1e30f;
        }

        // ---- online softmax, per-lane query (exp2 domain) ----
        float pm = s[0][0];
        #pragma unroll
        for (int c = 0; c < 4; ++c)
            #pragma unroll
            for (int r = 0; r < 4; ++r) pm = fmaxf(pm, s[c][r]);
        pm = fmaxf(pm, __shfl_xor(pm, 16, 64));
        pm = fmaxf(pm, __shfl_xor(pm, 32, 64));

        const float mn = fmaxf(m, pm);
        const float cr = exp2f(m - mn);
        m = mn;
        float ts = 0.0f;
        #pragma unroll
        for (int c = 0; c < 4; ++c)
            #pragma unroll
            for (int r = 0; r < 4; ++r) {
                const float p = exp2f(s[c][r] - mn);
                s[c][r] = p;
                ts += p;
            }
        ts += __shfl_xor(ts, 16, 64);
        ts += __shfl_xor(ts, 32, 64);
        l = l * cr + ts;

        // ---- P -> Pl[w][query ln][key]: 4-key runs, cvt_pk + b64 ----
        #pragma unroll
        for (int c = 0; c < 4; ++c) {
            uint2 pk;
            pk.x = cvt_pk_bf16(s[c][0], s[c][1]);
            pk.y = cvt_pk_bf16(s[c][2], s[c][3]);
            *reinterpret_cast<uint2*>(&Pl[w][ln][c * 16 + g * 4]) = pk;
        }

        // ---- rescale O (rows are queries g*4+r -> broadcast cr) ----
        float crr[4];
        #pragma unroll
        for (int r = 0; r < 4; ++r) crr[r] = __shfl(cr, g * 4 + r, 64);
        #pragma unroll
        for (int d = 0; d < 4; ++d)
            #pragma unroll
            for (int r = 0; r < 4; ++r) o[d][r] *= crr[r];

        // ---- PV ----
        __builtin_amdgcn_s_setprio(1);
        #pragma unroll
        for (int kk = 0; kk < 2; ++kk) {
            bf16x8 pf = *reinterpret_cast<const bf16x8*>(&Pl[w][ln][kk * 32 + kg8]);
            #pragma unroll
            for (int d = 0; d < 4; ++d) {
                bf16x8 vf = *reinterpret_cast<const bf16x8*>(
                    &Vb[(d * 16 + ln) * 64 + (((kk * 4 + g) ^ l7) << 3)]);
                o[d] = __builtin_amdgcn_mfma_f32_16x16x32_bf16(pf, vf, o[d], 0, 0, 0);
            }
        }
        __builtin_amdgcn_s_setprio(0);
        __syncthreads();
        cur ^= 1;
    }

    // ---- epilogue: normalize (broadcast 1/l to query rows) and store ----
    const float linv = 1.0f / l;
    float invr[4];
    #pragma unroll
    for (int r = 0; r < 4; ++r) invr[r] = __shfl(linv, g * 4 + r, 64);
    #pragma unroll
    for (int d = 0; d < 4; ++d)
        #pragma unroll
        for (int r = 0; r < 4; ++r) {
            const int q = q0 + w * 16 + g * 4 + r;
            Pg[(size_t)(b * S + q) * DM + h * 64 + d * 16 + ln] = f2bf(o[d][r] * invr[r]);
        }
}

// ---------------------------------------------------------------------------
// launch
// ---------------------------------------------------------------------------
extern "C" void kernel_launch(void* const* d_in, const int* in_sizes, int n_in,
                              void* d_out, int out_size, void* d_ws, size_t ws_size,
                              hipStream_t stream) {
    const float* x  = (const float*)d_in[0];
    const float* Wq = (const float*)d_in[1];
    const float* bq = (const float*)d_in[2];
    const float* Wk = (const float*)d_in[3];
    const float* bk = (const float*)d_in[4];
    const float* Wv = (const float*)d_in[5];
    const float* bv = (const float*)d_in[6];
    const float* Wo = (const float*)d_in[7];
    const float* bo = (const float*)d_in[8];
    float* out = (float*)d_out;

    u16* xb   = (u16*)d_ws;                      // MT*DM ; later aliased as Pb
    u16* wqb  = xb   + (size_t)MT * DM;
    u16* wkb  = wqb  + (size_t)DM * DM;
    u16* wvb  = wkb  + (size_t)DM * DM;
    u16* wob  = wvb  + (size_t)DM * DM;
    u16* QKVb = wob  + (size_t)DM * DM;          // MT*3DM
    u16* Vtg  = QKVb + (size_t)MT * 3 * DM;      // MT*DM
    u16* Pb   = xb;                              // alias: x no longer needed

    const int nX = MT * DM;
    const int nW = DM * DM;

    cvt_f32_bf16<<<dim3((nX / 4 + 255) / 256), dim3(256), 0, stream>>>(x,  xb,  nX / 4);
    cvt_f32_bf16<<<dim3((nW / 4 + 255) / 256), dim3(256), 0, stream>>>(Wq, wqb, nW / 4);
    cvt_f32_bf16<<<dim3((nW / 4 + 255) / 256), dim3(256), 0, stream>>>(Wk, wkb, nW / 4);
    cvt_f32_bf16<<<dim3((nW / 4 + 255) / 256), dim3(256), 0, stream>>>(Wv, wvb, nW / 4);
    cvt_f32_bf16<<<dim3((nW / 4 + 255) / 256), dim3(256), 0, stream>>>(Wo, wob, nW / 4);

    // fused QKV projection; Q segment scaled by 0.125*log2(e) for exp2 softmax
    const float SCL = 0.125f * 1.4426950408889634f;
    gemm_lds<true><<<dim3(MT / 128, 3 * DM / 128), dim3(256), 0, stream>>>(
        xb, wqb, bq, bk, bv, SCL, 1.0f, 1.0f, QKVb, DM, LDQ);

    transpose_v<<<dim3(BB * NH, S / 64), dim3(256), 0, stream>>>(QKVb, Vtg);

    attn_mfma<<<dim3(BB * NH, S / 64), dim3(256), 0, stream>>>(QKVb, Vtg, Pb);

    gemm_lds<false><<<dim3(MT / 128, DM / 128), dim3(256), 0, stream>>>(
        Pb, wob, bo, bo, bo, 1.0f, 1.0f, 1.0f, out, DM, DM);
}